// Round 5
// baseline (13651.949 us; speedup 1.0000x reference)
//
#include <hip/hip_runtime.h>
#include <hip/hip_bf16.h>

typedef unsigned short u16;
typedef unsigned int u32;

// ---------------- helpers ----------------
__device__ __forceinline__ float bf2f(u16 u) { return __uint_as_float(((u32)u) << 16); }
__device__ __forceinline__ u16 f2bf(float f) {
  u32 x = __float_as_uint(f);
  return (u16)((x + 0x7FFFu + ((x >> 16) & 1u)) >> 16);
}
__device__ __forceinline__ void up4(uint2 r, float* o) {
  o[0] = bf2f((u16)(r.x & 0xFFFF)); o[1] = bf2f((u16)(r.x >> 16));
  o[2] = bf2f((u16)(r.y & 0xFFFF)); o[3] = bf2f((u16)(r.y >> 16));
}
__device__ __forceinline__ uint2 pk4(const float* o) {
  uint2 r;
  r.x = (u32)f2bf(o[0]) | ((u32)f2bf(o[1]) << 16);
  r.y = (u32)f2bf(o[2]) | ((u32)f2bf(o[3]) << 16);
  return r;
}
__device__ __forceinline__ float wsum64(float v) {
#pragma unroll
  for (int o = 32; o > 0; o >>= 1) v += __shfl_xor(v, o, 64);
  return v;
}
__device__ __forceinline__ float sigm(float x) { return 1.0f / (1.0f + __expf(-x)); }

__global__ __launch_bounds__(256) void fill_kernel(float* __restrict__ out, int n, float v) {
  int i = blockIdx.x * 256 + threadIdx.x;
  if (i < n) out[i] = v;
}

// ---------------- CSR build ----------------
__global__ __launch_bounds__(256) void csr_hist(const int* __restrict__ dst,
                                                int* __restrict__ hist, int ne) {
  int e = blockIdx.x * 256 + threadIdx.x;
  if (e < ne) atomicAdd(&hist[dst[e]], 1);
}
__global__ __launch_bounds__(1024) void scan1(const int* __restrict__ in,
                                              int* __restrict__ out1, int* __restrict__ bsum, int n) {
  __shared__ int s[1024];
  int i = blockIdx.x * 1024 + threadIdx.x;
  int v = (i < n) ? in[i] : 0;
  s[threadIdx.x] = v; __syncthreads();
  for (int off = 1; off < 1024; off <<= 1) {
    int t = (threadIdx.x >= (u32)off) ? s[threadIdx.x - off] : 0;
    __syncthreads();
    s[threadIdx.x] += t;
    __syncthreads();
  }
  if (i < n) out1[i] = s[threadIdx.x];
  if (threadIdx.x == 1023) bsum[blockIdx.x] = s[1023];
}
__global__ __launch_bounds__(128) void scan2(int* __restrict__ bsum, int nb) {
  __shared__ int s[128];
  int v = (threadIdx.x < (u32)nb) ? bsum[threadIdx.x] : 0;
  s[threadIdx.x] = v; __syncthreads();
  for (int off = 1; off < 128; off <<= 1) {
    int t = (threadIdx.x >= (u32)off) ? s[threadIdx.x - off] : 0;
    __syncthreads();
    s[threadIdx.x] += t;
    __syncthreads();
  }
  if (threadIdx.x < (u32)nb) bsum[threadIdx.x] = threadIdx.x ? s[threadIdx.x - 1] : 0;
}
__global__ __launch_bounds__(256) void scan3(int* __restrict__ offs,
                                             const int* __restrict__ bsum, int n) {
  int i = blockIdx.x * 256 + threadIdx.x;
  if (i == 0) offs[0] = 0;
  if (i < n) offs[1 + i] += bsum[i >> 10];
}
__global__ __launch_bounds__(256) void csr_scatter(const int* __restrict__ dst,
                                                   int* __restrict__ cursor,
                                                   const int* __restrict__ offs,
                                                   int* __restrict__ eid, int ne) {
  int e = blockIdx.x * 256 + threadIdx.x;
  if (e < ne) {
    int d = dst[e];
    int p = offs[d] + atomicAdd(&cursor[d], 1);
    eid[p] = e;
  }
}

// ---------------- embeddings ----------------
__global__ __launch_bounds__(256) void embed2_kernel(
    const float* __restrict__ xin, const float* __restrict__ W1,
    const float* __restrict__ b1, const float* __restrict__ ln1,
    const float* __restrict__ W2, const float* __restrict__ b2,
    const float* __restrict__ ln2, u16* __restrict__ out, int rows,
    int bins, float vmin, float vmax) {
  int row = blockIdx.x;
  if (row >= rows) return;
  __shared__ float rbf_s[80];
  __shared__ float t1[64];
  __shared__ float red[8];
  int tid = threadIdx.x;
  float xv = xin[row];
  float rng = vmax - vmin;
  float step = rng / (float)(bins - 1);
  float gamma = 0.5f * ((float)bins / rng) * ((float)bins / rng);
  if (tid < bins) {
    float d = xv - (vmin + tid * step);
    rbf_s[tid] = __expf(-gamma * d * d);
  }
  __syncthreads();
  if (tid < 64) {
    float u = b1[tid];
    for (int k = 0; k < bins; ++k) u = fmaf(rbf_s[k], W1[k * 64 + tid], u);
    float s = wsum64(u), s2 = wsum64(u * u);
    float m = s * (1.f / 64.f), var = s2 * (1.f / 64.f) - m * m;
    float t = (u - m) * rsqrtf(var + 1e-5f) * ln1[tid] + ln1[64 + tid];
    t1[tid] = t * sigm(t);
  }
  __syncthreads();
  float v = b2[tid];
#pragma unroll 8
  for (int k = 0; k < 64; ++k) v = fmaf(t1[k], W2[k * 256 + tid], v);
  float s = wsum64(v), s2 = wsum64(v * v);
  int lane = tid & 63, wid = tid >> 6;
  if (lane == 0) { red[wid] = s; red[4 + wid] = s2; }
  __syncthreads();
  s = red[0] + red[1] + red[2] + red[3];
  s2 = red[4] + red[5] + red[6] + red[7];
  float m = s * (1.f / 256.f), var = s2 * (1.f / 256.f) - m * m;
  float t = (v - m) * rsqrtf(var + 1e-5f) * ln2[tid] + ln2[256 + tid];
  out[(size_t)row * 256 + tid] = f2bf(t * sigm(t));
}

__global__ __launch_bounds__(256) void atom_embed_kernel(
    const float* __restrict__ af, const float* __restrict__ W,
    const float* __restrict__ b, const float* __restrict__ ln,
    u16* __restrict__ out, int rows) {
  int row = blockIdx.x;
  if (row >= rows) return;
  __shared__ float a_s[92];
  __shared__ float red[8];
  int tid = threadIdx.x;
  if (tid < 92) a_s[tid] = af[(size_t)row * 92 + tid];
  __syncthreads();
  float v = b[tid];
#pragma unroll 4
  for (int k = 0; k < 92; ++k) v = fmaf(a_s[k], W[k * 256 + tid], v);
  float s = wsum64(v), s2 = wsum64(v * v);
  int lane = tid & 63, wid = tid >> 6;
  if (lane == 0) { red[wid] = s; red[4 + wid] = s2; }
  __syncthreads();
  s = red[0] + red[1] + red[2] + red[3];
  s2 = red[4] + red[5] + red[6] + red[7];
  float m = s * (1.f / 256.f), var = s2 * (1.f / 256.f) - m * m;
  float t = (v - m) * rsqrtf(var + 1e-5f) * ln[tid] + ln[256 + tid];
  out[(size_t)row * 256 + tid] = f2bf(t * sigm(t));
}

// ---------------- GEMM: C[M,Nc](bf16) = A[M,256](bf16) @ W[256,Nc](f32) + bias ----------------
// W slabs are [256,256] row-major; col-block bn uses slab (bn>>8)*slab_step (handles W0|W4, W1|W3).
// If offs!=nullptr: rows are CSR-gathered: row0=offs[v0], M=min(offs[v1]-row0, Mcap), A-row=eid[row0+r].
#define BM 128
#define BN 128
__global__ __launch_bounds__(256) void gemm_k256(
    const u16* __restrict__ A, const float* __restrict__ Wbase,
    const float* __restrict__ bias, u16* __restrict__ C,
    int M, int ldc, int slab_step,
    const int* __restrict__ eid, const int* __restrict__ offs, int v0, int v1) {
  int row0 = 0, Mloc = M;
  if (offs) {
    row0 = offs[v0];
    int r1 = offs[v1];
    int mm = r1 - row0;
    Mloc = mm < M ? mm : M;
  }
  int bm = blockIdx.x * BM;
  if (bm >= Mloc) return;
  __shared__ float As[16][BM + 4];
  __shared__ float Ws[16][BN + 4];
  int tid = threadIdx.x;
  int bn = blockIdx.y * BN;
  const float* Wp = Wbase + (size_t)((bn >> 8) * slab_step) * 65536 + (bn & 255);
  const float* bp = bias + (size_t)((bn >> 8) * slab_step) * 256 + (bn & 255);
  int tx = tid & 15, ty = tid >> 4;
  int arow = tid >> 1, acol = (tid & 1) * 8;
  int wrow = tid >> 4, wcol = (tid & 15) * 8;
  int ga = min(bm + arow, Mloc - 1);
  int grow = eid ? eid[row0 + ga] : ga;
  const u16* Ap = A + (size_t)grow * 256 + acol;
  const float* Wp2 = Wp + (size_t)wrow * 256 + wcol;
  float acc[8][8];
#pragma unroll
  for (int i = 0; i < 8; ++i)
#pragma unroll
    for (int j = 0; j < 8; ++j) acc[i][j] = 0.f;

  for (int kt = 0; kt < 16; ++kt) {
    uint4 araw = *(const uint4*)(Ap + kt * 16);  // 8 bf16
    float4 w0 = *(const float4*)(Wp2 + (size_t)kt * 16 * 256);
    float4 w1 = *(const float4*)(Wp2 + (size_t)kt * 16 * 256 + 4);
    __syncthreads();
    As[acol + 0][arow] = bf2f((u16)(araw.x & 0xFFFF));
    As[acol + 1][arow] = bf2f((u16)(araw.x >> 16));
    As[acol + 2][arow] = bf2f((u16)(araw.y & 0xFFFF));
    As[acol + 3][arow] = bf2f((u16)(araw.y >> 16));
    As[acol + 4][arow] = bf2f((u16)(araw.z & 0xFFFF));
    As[acol + 5][arow] = bf2f((u16)(araw.z >> 16));
    As[acol + 6][arow] = bf2f((u16)(araw.w & 0xFFFF));
    As[acol + 7][arow] = bf2f((u16)(araw.w >> 16));
    *(float4*)&Ws[wrow][wcol] = w0;
    *(float4*)&Ws[wrow][wcol + 4] = w1;
    __syncthreads();
#pragma unroll
    for (int kk = 0; kk < 16; ++kk) {
      float4 af0 = *(const float4*)&As[kk][ty * 8];
      float4 af1 = *(const float4*)&As[kk][ty * 8 + 4];
      float4 wf0 = *(const float4*)&Ws[kk][tx * 8];
      float4 wf1 = *(const float4*)&Ws[kk][tx * 8 + 4];
      float av[8] = {af0.x, af0.y, af0.z, af0.w, af1.x, af1.y, af1.z, af1.w};
      float wv[8] = {wf0.x, wf0.y, wf0.z, wf0.w, wf1.x, wf1.y, wf1.z, wf1.w};
#pragma unroll
      for (int i = 0; i < 8; ++i)
#pragma unroll
        for (int j = 0; j < 8; ++j) acc[i][j] = fmaf(av[i], wv[j], acc[i][j]);
    }
  }
#pragma unroll
  for (int i = 0; i < 8; ++i) {
    int m = bm + ty * 8 + i;
    if (m < Mloc) {
      uint4 pk;
      u32* pkp = (u32*)&pk;
#pragma unroll
      for (int jj = 0; jj < 4; ++jj) {
        float c0 = acc[i][2 * jj] + bp[tx * 8 + 2 * jj];
        float c1 = acc[i][2 * jj + 1] + bp[tx * 8 + 2 * jj + 1];
        pkp[jj] = (u32)f2bf(c0) | ((u32)f2bf(c1) << 16);
      }
      *(uint4*)(C + (size_t)m * ldc + bn + tx * 8) = pk;
    }
  }
}

// ---------------- fused EGGC: wave per dst node, walks CSR edges ----------------
// G0Bh row (512): [0:256)=h@W0+b0 (src gate), [256:512)=h@W4+b4 (dst_update)
// G1Ah row (512): [0:256)=h@W1+b1 (dst gate), [256:512)=h@W3+b3 (src_update); chunk-local
// Pe: e[eid]@W2+b2, chunk-local CSR order. e updated in place (edge out), h in place (node out).
__global__ __launch_bounds__(256) void eggc_fused(
    const int* __restrict__ srcArr, const int* __restrict__ eid,
    const int* __restrict__ offs, int v0, int v1,
    const u16* __restrict__ G0Bh, const u16* __restrict__ G1Ah,
    const u16* __restrict__ Pe, int ecap,
    u16* __restrict__ e, u16* __restrict__ h,
    const float* __restrict__ lnS, const float* __restrict__ lnB) {
  int wv = (blockIdx.x * 256 + threadIdx.x) >> 6;
  int v = v0 + wv;
  if (v >= v1) return;
  int lane = threadIdx.x & 63;
  int f = lane * 4;
  int row0 = offs[v0];
  int r0 = offs[v], r1 = offs[v + 1];
  float lwe[4], lbe[4], lwn[4], lbn[4];
#pragma unroll
  for (int k = 0; k < 4; ++k) {
    lwe[k] = lnS[f + k];       lbe[k] = lnB[f + k];
    lwn[k] = lnS[256 + f + k]; lbn[k] = lnB[256 + f + k];
  }
  float g1v[4], ah[4];
  up4(*(const uint2*)(G1Ah + (size_t)(v - v0) * 512 + f), g1v);
  up4(*(const uint2*)(G1Ah + (size_t)(v - v0) * 512 + 256 + f), ah);
  float ssh[4] = {0, 0, 0, 0}, ssm[4] = {0, 0, 0, 0};
  for (int i = r0; i < r1; ++i) {
    int li = i - row0;
    if (li >= ecap) break;  // statistical cap; never expected to trigger
    int eidx = eid[i];
    int sv = srcArr[eidx];
    float g0[4], bh[4], pe[4], ev[4];
    up4(*(const uint2*)(G0Bh + (size_t)sv * 512 + f), g0);
    up4(*(const uint2*)(G0Bh + (size_t)sv * 512 + 256 + f), bh);
    up4(*(const uint2*)(Pe + (size_t)li * 256 + f), pe);
    up4(*(const uint2*)(e + (size_t)eidx * 256 + f), ev);
    float t[4];
#pragma unroll
    for (int k = 0; k < 4; ++k) {
      float sg = sigm(g0[k] + g1v[k] + pe[k]);
      t[k] = sg * ev[k];
      ssh[k] = fmaf(bh[k], sg, ssh[k]);
      ssm[k] += sg;
    }
    float s1 = wsum64(t[0] + t[1] + t[2] + t[3]);
    float s2 = wsum64(t[0] * t[0] + t[1] * t[1] + t[2] * t[2] + t[3] * t[3]);
    float mn = s1 * (1.f / 256.f);
    float rs = rsqrtf(s2 * (1.f / 256.f) - mn * mn + 1e-5f);
    float o[4];
#pragma unroll
    for (int k = 0; k < 4; ++k) o[k] = (t[k] - mn) * rs * lwe[k] + lbe[k];
    *(uint2*)(e + (size_t)eidx * 256 + f) = pk4(o);
  }
  float tt[4];
#pragma unroll
  for (int k = 0; k < 4; ++k) tt[k] = ah[k] + ssh[k] / (ssm[k] + 1e-8f);
  float s1 = wsum64(tt[0] + tt[1] + tt[2] + tt[3]);
  float s2 = wsum64(tt[0] * tt[0] + tt[1] * tt[1] + tt[2] * tt[2] + tt[3] * tt[3]);
  float mn = s1 * (1.f / 256.f);
  float rs = rsqrtf(s2 * (1.f / 256.f) - mn * mn + 1e-5f);
  float o[4];
#pragma unroll
  for (int k = 0; k < 4; ++k) o[k] = (tt[k] - mn) * rs * lwn[k] + lbn[k];
  *(uint2*)(h + (size_t)v * 256 + f) = pk4(o);
}

// ---------------- readout ----------------
__global__ __launch_bounds__(256) void pool_acc(
    const u16* __restrict__ x, const int* __restrict__ gid,
    float* __restrict__ out, float* __restrict__ cnt, int n) {
  int v = (blockIdx.x * 256 + threadIdx.x) >> 6;
  if (v >= n) return;
  int lane = threadIdx.x & 63;
  int f = lane * 4;
  int g = gid[v];
  float xv[4];
  up4(*(const uint2*)(x + (size_t)v * 256 + f), xv);
  float* p = out + (size_t)g * 256 + f;
  unsafeAtomicAdd(p + 0, xv[0]);
  unsafeAtomicAdd(p + 1, xv[1]);
  unsafeAtomicAdd(p + 2, xv[2]);
  unsafeAtomicAdd(p + 3, xv[3]);
  if (lane == 0) unsafeAtomicAdd(cnt + g, 1.0f);
}
__global__ __launch_bounds__(256) void pool_div(float* __restrict__ out,
                                                const float* __restrict__ cnt, int n) {
  int i = blockIdx.x * blockDim.x + threadIdx.x;
  if (i < n) out[i] /= fmaxf(cnt[i >> 8], 1.0f);
}

// ---------------- host ----------------
extern "C" void kernel_launch(void* const* d_in, const int* in_sizes, int n_in,
                              void* d_out, int out_size, void* d_ws, size_t ws_size,
                              hipStream_t stream) {
  const float* atom_features = (const float*)d_in[0];
  const float* bondlength    = (const float*)d_in[1];
  const float* angle_h       = (const float*)d_in[2];
  const int*   src           = (const int*)d_in[3];
  const int*   dst           = (const int*)d_in[4];
  const int*   lg_src        = (const int*)d_in[5];
  const int*   lg_dst        = (const int*)d_in[6];
  const int*   gid           = (const int*)d_in[7];
  const float* atom_W  = (const float*)d_in[8];
  const float* atom_b  = (const float*)d_in[9];
  const float* atom_ln = (const float*)d_in[10];
  const float* edge_W1 = (const float*)d_in[11];
  const float* edge_b1 = (const float*)d_in[12];
  const float* edge_ln1= (const float*)d_in[13];
  const float* edge_W2 = (const float*)d_in[14];
  const float* edge_b2 = (const float*)d_in[15];
  const float* edge_ln2= (const float*)d_in[16];
  const float* ang_W1  = (const float*)d_in[17];
  const float* ang_b1  = (const float*)d_in[18];
  const float* ang_ln1 = (const float*)d_in[19];
  const float* ang_W2  = (const float*)d_in[20];
  const float* ang_b2  = (const float*)d_in[21];
  const float* ang_ln2 = (const float*)d_in[22];
  const float* conv_W  = (const float*)d_in[23];
  const float* conv_b  = (const float*)d_in[24];
  const float* conv_lns= (const float*)d_in[25];
  const float* conv_lnb= (const float*)d_in[26];

  int N = in_sizes[0] / 92;
  int E = in_sizes[1];
  int T = in_sizes[2];

  // ---- workspace layout (bytes) ----
  char* ws = (char*)d_ws;
  size_t o = 0;
  auto alloc = [&](size_t bytes) { size_t r = o; o = (o + bytes + 255) & ~(size_t)255; return r; };
  u16* z     = (u16*)(ws + alloc((size_t)T * 512));
  u16* y     = (u16*)(ws + alloc((size_t)E * 512));
  u16* x     = (u16*)(ws + alloc((size_t)N * 512));
  int* eidL  = (int*)(ws + alloc((size_t)T * 4));
  int* offsL = (int*)(ws + alloc((size_t)(E + 1) * 4));
  int* eidA  = (int*)(ws + alloc((size_t)E * 4));
  int* offsA = (int*)(ws + alloc((size_t)(N + 1) * 4));
  int* tmp   = (int*)(ws + alloc((size_t)(E > N ? E : N) * 4));  // hist / cursor
  int* bsum  = (int*)(ws + alloc(1024));
  float* cnt = (float*)(ws + alloc(1024));
  size_t layer_base = o;

  if (ws_size < layer_base + (size_t)512 * 1024) {
    fill_kernel<<<(out_size + 255) / 256, 256, 0, stream>>>(
        (float*)d_out, out_size, (float)(ws_size >> 20));
    return;
  }
  size_t avail = ws_size - layer_base;

  // chunk config per graph type
  auto pick = [&](long long nn_, long long ne_, int& VC, int& EC) -> bool {
    long long sub = (long long)avail - nn_ * 1024;  // minus G0Bh
    const long long cands[6] = {16384, 8192, 4096, 2048, 1024, 512};
    for (int ci = 0; ci < 6; ++ci) {
      long long vc = cands[ci] > nn_ ? nn_ : cands[ci];
      long long ecreq = ne_ * vc / nn_ + vc / 2 + 2048;
      if (ecreq > ne_) ecreq = ne_;
      if (vc * 1024 + ecreq * 512 <= sub) {
        long long ec = (sub - vc * 1024) / 512;
        if (ec > ne_) ec = ne_;
        VC = (int)vc; EC = (int)ec;
        return true;
      }
    }
    return false;
  };
  int VCL = 0, ECL = 0, VCA = 0, ECA = 0;
  if (!pick(E, T, VCL, ECL) || !pick(N, E, VCA, ECA)) {
    fill_kernel<<<(out_size + 255) / 256, 256, 0, stream>>>(
        (float*)d_out, out_size, 1000000.0f + (float)(ws_size >> 20));
    return;
  }

  // ---- CSR build (line: dst=lg_dst over E nodes; atom: dst over N nodes) ----
  auto build_csr = [&](const int* dvec, int ne_, int nn_, int* offs_, int* eid_) {
    hipMemsetAsync(tmp, 0, (size_t)nn_ * 4, stream);
    csr_hist<<<(ne_ + 255) / 256, 256, 0, stream>>>(dvec, tmp, ne_);
    int nb = (nn_ + 1023) / 1024;
    scan1<<<nb, 1024, 0, stream>>>(tmp, offs_ + 1, bsum, nn_);
    scan2<<<1, 128, 0, stream>>>(bsum, nb);
    scan3<<<(nn_ + 255) / 256, 256, 0, stream>>>(offs_, bsum, nn_);
    hipMemsetAsync(tmp, 0, (size_t)nn_ * 4, stream);
    csr_scatter<<<(ne_ + 255) / 256, 256, 0, stream>>>(dvec, tmp, offs_, eid_, ne_);
  };
  build_csr(lg_dst, T, E, offsL, eidL);
  build_csr(dst, E, N, offsA, eidA);

  // ---- embeddings ----
  embed2_kernel<<<T, 256, 0, stream>>>(angle_h, ang_W1, ang_b1, ang_ln1,
                                       ang_W2, ang_b2, ang_ln2, z, T, 40, -1.f, 1.f);
  embed2_kernel<<<E, 256, 0, stream>>>(bondlength, edge_W1, edge_b1, edge_ln1,
                                       edge_W2, edge_b2, edge_ln2, y, E, 80, 0.f, 8.f);
  atom_embed_kernel<<<N, 256, 0, stream>>>(atom_features, atom_W, atom_b, atom_ln, x, N);

  // ---- 12 EGGC layers ----
  for (int l = 0; l < 12; ++l) {
    const float* Wl  = conv_W  + (size_t)l * 5 * 65536;
    const float* bl  = conv_b  + (size_t)l * 5 * 256;
    const float* lnS = conv_lns + (size_t)l * 512;
    const float* lnB = conv_lnb + (size_t)l * 512;
    bool line = (l < 8) && ((l & 1) == 0);
    u16* h = line ? y : x;
    u16* e = line ? z : y;
    const int* sp   = line ? lg_src : src;
    const int* eidG = line ? eidL : eidA;
    const int* offs = line ? offsL : offsA;
    int nn = line ? E : N;
    int ne = line ? T : E;
    int VC = line ? VCL : VCA;
    int EC = line ? ECL : ECA;

    u16* G0Bh = (u16*)(ws + layer_base);
    u16* G1Ah = G0Bh + (size_t)nn * 512;
    u16* Pe   = G1Ah + (size_t)VC * 512;

    // G0Bh = h @ [W0|W4] + [b0|b4]   (slab_step=4)
    dim3 g0((nn + 127) / 128, 4);
    gemm_k256<<<g0, 256, 0, stream>>>(h, Wl, bl, G0Bh, nn, 512, 4,
                                      nullptr, nullptr, 0, 0);
    for (int v0 = 0; v0 < nn; v0 += VC) {
      int v1 = min(v0 + VC, nn);
      int cn = v1 - v0;
      // G1Ah = h[v0:v1] @ [W1|W3] + [b1|b3]  (slab_step=2)
      dim3 g1((cn + 127) / 128, 4);
      gemm_k256<<<g1, 256, 0, stream>>>(h + (size_t)v0 * 256, Wl + 65536, bl + 256,
                                        G1Ah, cn, 512, 2, nullptr, nullptr, 0, 0);
      // Pe = e[eid[offs[v0]:offs[v1]]] @ W2 + b2 (row gather, chunk-local)
      dim3 g2((EC + 127) / 128, 2);
      gemm_k256<<<g2, 256, 0, stream>>>(e, Wl + 2 * 65536, bl + 2 * 256,
                                        Pe, EC, 256, 1, eidG, offs, v0, v1);
      // fused gate + edge-LN (in place on e) + gated-mean + node-LN (in place on h)
      eggc_fused<<<(cn + 3) / 4, 256, 0, stream>>>(sp, eidG, offs, v0, v1,
                                                   G0Bh, G1Ah, Pe, EC, e, h, lnS, lnB);
    }
  }

  // ---- readout ----
  hipMemsetAsync(d_out, 0, (size_t)out_size * sizeof(float), stream);
  hipMemsetAsync(cnt, 0, 256 * sizeof(float), stream);
  pool_acc<<<(N + 3) / 4, 256, 0, stream>>>(x, gid, (float*)d_out, cnt, N);
  pool_div<<<(out_size + 255) / 256, 256, 0, stream>>>((float*)d_out, cnt, out_size);
}

// Round 6
// 7630.698 us; speedup vs baseline: 1.7891x; 1.7891x over previous
//
#include <hip/hip_runtime.h>
#include <hip/hip_bf16.h>

typedef unsigned short u16;
typedef unsigned int u32;
typedef __attribute__((ext_vector_type(8))) short short8;
typedef __attribute__((ext_vector_type(4))) float f32x4;

// ---------------- helpers ----------------
__device__ __forceinline__ float bf2f(u16 u) { return __uint_as_float(((u32)u) << 16); }
__device__ __forceinline__ u16 f2bf(float f) {
  u32 x = __float_as_uint(f);
  return (u16)((x + 0x7FFFu + ((x >> 16) & 1u)) >> 16);
}
__device__ __forceinline__ void up4(uint2 r, float* o) {
  o[0] = bf2f((u16)(r.x & 0xFFFF)); o[1] = bf2f((u16)(r.x >> 16));
  o[2] = bf2f((u16)(r.y & 0xFFFF)); o[3] = bf2f((u16)(r.y >> 16));
}
__device__ __forceinline__ uint2 pk4(const float* o) {
  uint2 r;
  r.x = (u32)f2bf(o[0]) | ((u32)f2bf(o[1]) << 16);
  r.y = (u32)f2bf(o[2]) | ((u32)f2bf(o[3]) << 16);
  return r;
}
__device__ __forceinline__ float wsum64(float v) {
#pragma unroll
  for (int o = 32; o > 0; o >>= 1) v += __shfl_xor(v, o, 64);
  return v;
}
__device__ __forceinline__ float sigm(float x) { return 1.0f / (1.0f + __expf(-x)); }

__global__ __launch_bounds__(256) void fill_kernel(float* __restrict__ out, int n, float v) {
  int i = blockIdx.x * 256 + threadIdx.x;
  if (i < n) out[i] = v;
}

// ---------------- weight transpose: in[k][n] f32 -> out[n][k] bf16 ----------------
// R=k-rows, Ccols=n-cols, both multiples of 64. blockIdx.z = slab (R*Ccols elements each).
__global__ __launch_bounds__(256) void wtrans(const float* __restrict__ in,
                                              u16* __restrict__ out, int R, int Ccols) {
  __shared__ float t[64][65];
  const float* ip = in + (size_t)blockIdx.z * R * Ccols;
  u16* op = out + (size_t)blockIdx.z * R * Ccols;
  int kb = blockIdx.x * 64, nb = blockIdx.y * 64;
  int lr = threadIdx.x >> 4, lc = (threadIdx.x & 15) * 4;
#pragma unroll
  for (int p = 0; p < 4; ++p) {
    int k = lr + p * 16;
    float4 v = *(const float4*)(ip + (size_t)(kb + k) * Ccols + nb + lc);
    t[k][lc + 0] = v.x; t[k][lc + 1] = v.y; t[k][lc + 2] = v.z; t[k][lc + 3] = v.w;
  }
  __syncthreads();
#pragma unroll
  for (int p = 0; p < 4; ++p) {
    int n = lr + p * 16;
    uint2 pk;
    pk.x = (u32)f2bf(t[lc + 0][n]) | ((u32)f2bf(t[lc + 1][n]) << 16);
    pk.y = (u32)f2bf(t[lc + 2][n]) | ((u32)f2bf(t[lc + 3][n]) << 16);
    *(uint2*)(op + (size_t)(nb + n) * R + kb + lc) = pk;
  }
}

// ---------------- CSR build ----------------
__global__ __launch_bounds__(256) void csr_hist(const int* __restrict__ dst,
                                                int* __restrict__ hist, int ne) {
  int e = blockIdx.x * 256 + threadIdx.x;
  if (e < ne) atomicAdd(&hist[dst[e]], 1);
}
__global__ __launch_bounds__(1024) void scan1(const int* __restrict__ in,
                                              int* __restrict__ out1, int* __restrict__ bsum, int n) {
  __shared__ int s[1024];
  int i = blockIdx.x * 1024 + threadIdx.x;
  int v = (i < n) ? in[i] : 0;
  s[threadIdx.x] = v; __syncthreads();
  for (int off = 1; off < 1024; off <<= 1) {
    int t = (threadIdx.x >= (u32)off) ? s[threadIdx.x - off] : 0;
    __syncthreads();
    s[threadIdx.x] += t;
    __syncthreads();
  }
  if (i < n) out1[i] = s[threadIdx.x];
  if (threadIdx.x == 1023) bsum[blockIdx.x] = s[1023];
}
__global__ __launch_bounds__(128) void scan2(int* __restrict__ bsum, int nb) {
  __shared__ int s[128];
  int v = (threadIdx.x < (u32)nb) ? bsum[threadIdx.x] : 0;
  s[threadIdx.x] = v; __syncthreads();
  for (int off = 1; off < 128; off <<= 1) {
    int t = (threadIdx.x >= (u32)off) ? s[threadIdx.x - off] : 0;
    __syncthreads();
    s[threadIdx.x] += t;
    __syncthreads();
  }
  if (threadIdx.x < (u32)nb) bsum[threadIdx.x] = threadIdx.x ? s[threadIdx.x - 1] : 0;
}
__global__ __launch_bounds__(256) void scan3(int* __restrict__ offs,
                                             const int* __restrict__ bsum, int n) {
  int i = blockIdx.x * 256 + threadIdx.x;
  if (i == 0) offs[0] = 0;
  if (i < n) offs[1 + i] += bsum[i >> 10];
}
__global__ __launch_bounds__(256) void csr_scatter(const int* __restrict__ dst,
                                                   int* __restrict__ cursor,
                                                   const int* __restrict__ offs,
                                                   int* __restrict__ eid, int ne) {
  int e = blockIdx.x * 256 + threadIdx.x;
  if (e < ne) {
    int d = dst[e];
    int p = offs[d] + atomicAdd(&cursor[d], 1);
    eid[p] = e;
  }
}

// ---------------- embeddings ----------------
// stage1: wave per row: rbf(bins) -> W1[bins,64]+b1 -> LN64 -> SiLU -> t1 bf16[rows,64]
__global__ __launch_bounds__(256) void embed_s1(
    const float* __restrict__ xin, const float* __restrict__ W1,
    const float* __restrict__ b1, const float* __restrict__ ln1,
    u16* __restrict__ t1, int rows, int bins, float vmin, float vmax) {
  int row = (blockIdx.x * 256 + threadIdx.x) >> 6;
  if (row >= rows) return;
  int lane = threadIdx.x & 63;
  float xv = xin[row];
  float rng = vmax - vmin;
  float step = rng / (float)(bins - 1);
  float gamma = 0.5f * ((float)bins / rng) * ((float)bins / rng);
  float rb = 0.f, rb2 = 0.f;
  if (lane < bins) {
    float d = xv - (vmin + lane * step);
    rb = __expf(-gamma * d * d);
  }
  if (bins > 64 && lane < bins - 64) {
    float d = xv - (vmin + (lane + 64) * step);
    rb2 = __expf(-gamma * d * d);
  }
  float u = b1[lane];
  int k1 = bins < 64 ? bins : 64;
  for (int k = 0; k < k1; ++k) {
    float rv = __shfl(rb, k, 64);
    u = fmaf(rv, W1[k * 64 + lane], u);
  }
  for (int k = 64; k < bins; ++k) {
    float rv = __shfl(rb2, k - 64, 64);
    u = fmaf(rv, W1[k * 64 + lane], u);
  }
  float s = wsum64(u), s2 = wsum64(u * u);
  float m = s * (1.f / 64.f), var = s2 * (1.f / 64.f) - m * m;
  float t = (u - m) * rsqrtf(var + 1e-5f) * ln1[lane] + ln1[64 + lane];
  t1[(size_t)row * 64 + lane] = f2bf(t * sigm(t));
}

// epilogue: in-place LN(256) + SiLU on bf16 [rows,256]
__global__ __launch_bounds__(256) void ln_silu(u16* __restrict__ buf,
                                               const float* __restrict__ ln, int rows) {
  int row = (blockIdx.x * 256 + threadIdx.x) >> 6;
  if (row >= rows) return;
  int lane = threadIdx.x & 63;
  int f = lane * 4;
  float v[4];
  up4(*(const uint2*)(buf + (size_t)row * 256 + f), v);
  float s = wsum64(v[0] + v[1] + v[2] + v[3]);
  float s2 = wsum64(v[0] * v[0] + v[1] * v[1] + v[2] * v[2] + v[3] * v[3]);
  float m = s * (1.f / 256.f);
  float rs = rsqrtf(s2 * (1.f / 256.f) - m * m + 1e-5f);
  float o[4];
#pragma unroll
  for (int k = 0; k < 4; ++k) {
    float t = (v[k] - m) * rs * ln[f + k] + ln[256 + f + k];
    o[k] = t * sigm(t);
  }
  *(uint2*)(buf + (size_t)row * 256 + f) = pk4(o);
}

// atom_features[N,92] @ W[92,256] + b -> LN -> SiLU (small; stays VALU)
__global__ __launch_bounds__(256) void atom_embed_kernel(
    const float* __restrict__ af, const float* __restrict__ W,
    const float* __restrict__ b, const float* __restrict__ ln,
    u16* __restrict__ out, int rows) {
  int row = blockIdx.x;
  if (row >= rows) return;
  __shared__ float a_s[92];
  __shared__ float red[8];
  int tid = threadIdx.x;
  if (tid < 92) a_s[tid] = af[(size_t)row * 92 + tid];
  __syncthreads();
  float v = b[tid];
#pragma unroll 4
  for (int k = 0; k < 92; ++k) v = fmaf(a_s[k], W[k * 256 + tid], v);
  float s = wsum64(v), s2 = wsum64(v * v);
  int lane = tid & 63, wid = tid >> 6;
  if (lane == 0) { red[wid] = s; red[4 + wid] = s2; }
  __syncthreads();
  s = red[0] + red[1] + red[2] + red[3];
  s2 = red[4] + red[5] + red[6] + red[7];
  float m = s * (1.f / 256.f), var = s2 * (1.f / 256.f) - m * m;
  float t = (v - m) * rsqrtf(var + 1e-5f) * ln[tid] + ln[256 + tid];
  out[(size_t)row * 256 + tid] = f2bf(t * sigm(t));
}

// ---------------- MFMA GEMM: C[M,ldc](bf16) = A[M,K](bf16) @ W + bias ----------------
// Wt: bf16 transposed slabs [slab][256 n][K k]; col block bn -> slab (bn>>8)*slab_step.
// Computes swapped product D = Wt_frag x A_frag so stores are 8B-contiguous in n.
// Optional CSR row gather on A (eid/offs, rows offs[v0]..offs[v1], capped at M).
__global__ __launch_bounds__(256) void mfma_gemm(
    const u16* __restrict__ A, const u16* __restrict__ Wt,
    const float* __restrict__ bias, u16* __restrict__ C,
    int M, int K, int ldc, int slab_step,
    const int* __restrict__ eid, const int* __restrict__ offs, int v0, int v1) {
  int row0 = 0, Mloc = M;
  if (offs) {
    row0 = offs[v0];
    int mm = offs[v1] - row0;
    Mloc = mm < M ? mm : M;
  }
  int bm = blockIdx.x * 128;
  if (bm >= Mloc) return;
  int bn = blockIdx.y * 128;
  int slab = (bn >> 8) * slab_step;
  const u16* Wp = Wt + (size_t)slab * 256 * K + (size_t)(bn & 255) * K;
  const float* bp = bias + slab * 256 + (bn & 255);
  int tid = threadIdx.x;
  int w = tid >> 6, lane = tid & 63;
  int q = lane >> 4, r = lane & 15;
  int m0 = (w & 1) * 64;
  int n0 = (w >> 1) * 64;
  const u16* aptr[4];
#pragma unroll
  for (int mi = 0; mi < 4; ++mi) {
    int m = bm + m0 + mi * 16 + r;
    m = m < Mloc - 1 ? m : Mloc - 1;
    int g = eid ? eid[row0 + m] : m;
    aptr[mi] = A + (size_t)g * K + q * 8;
  }
  const u16* wptr[4];
#pragma unroll
  for (int ni = 0; ni < 4; ++ni)
    wptr[ni] = Wp + (size_t)(n0 + ni * 16 + r) * K + q * 8;
  f32x4 acc[4][4] = {};
  for (int kb = 0; kb < K; kb += 32) {
    short8 bfr[4], afr[4];
#pragma unroll
    for (int mi = 0; mi < 4; ++mi) bfr[mi] = *(const short8*)(aptr[mi] + kb);
#pragma unroll
    for (int ni = 0; ni < 4; ++ni) afr[ni] = *(const short8*)(wptr[ni] + kb);
#pragma unroll
    for (int mi = 0; mi < 4; ++mi)
#pragma unroll
      for (int ni = 0; ni < 4; ++ni)
        acc[mi][ni] = __builtin_amdgcn_mfma_f32_16x16x32_bf16(afr[ni], bfr[mi],
                                                              acc[mi][ni], 0, 0, 0);
  }
#pragma unroll
  for (int mi = 0; mi < 4; ++mi) {
    int m = bm + m0 + mi * 16 + r;
    if (m < Mloc) {
#pragma unroll
      for (int ni = 0; ni < 4; ++ni) {
        int n = n0 + ni * 16 + q * 4;  // col within 128-block
        float4 bv = *(const float4*)(bp + n);
        uint2 o;
        o.x = (u32)f2bf(acc[mi][ni].x + bv.x) | ((u32)f2bf(acc[mi][ni].y + bv.y) << 16);
        o.y = (u32)f2bf(acc[mi][ni].z + bv.z) | ((u32)f2bf(acc[mi][ni].w + bv.w) << 16);
        *(uint2*)(C + (size_t)m * ldc + bn + n) = o;
      }
    }
  }
}

// ---------------- fused EGGC: wave per dst node, walks CSR edges ----------------
__global__ __launch_bounds__(256) void eggc_fused(
    const int* __restrict__ srcArr, const int* __restrict__ eid,
    const int* __restrict__ offs, int v0, int v1,
    const u16* __restrict__ G0Bh, const u16* __restrict__ G1Ah,
    const u16* __restrict__ Pe, int ecap,
    u16* __restrict__ e, u16* __restrict__ h,
    const float* __restrict__ lnS, const float* __restrict__ lnB) {
  int wv = (blockIdx.x * 256 + threadIdx.x) >> 6;
  int v = v0 + wv;
  if (v >= v1) return;
  int lane = threadIdx.x & 63;
  int f = lane * 4;
  int row0 = offs[v0];
  int r0 = offs[v], r1 = offs[v + 1];
  float lwe[4], lbe[4], lwn[4], lbn[4];
#pragma unroll
  for (int k = 0; k < 4; ++k) {
    lwe[k] = lnS[f + k];       lbe[k] = lnB[f + k];
    lwn[k] = lnS[256 + f + k]; lbn[k] = lnB[256 + f + k];
  }
  float g1v[4], ah[4];
  up4(*(const uint2*)(G1Ah + (size_t)(v - v0) * 512 + f), g1v);
  up4(*(const uint2*)(G1Ah + (size_t)(v - v0) * 512 + 256 + f), ah);
  float ssh[4] = {0, 0, 0, 0}, ssm[4] = {0, 0, 0, 0};
  for (int i = r0; i < r1; ++i) {
    int li = i - row0;
    if (li >= ecap) break;
    int eidx = eid[i];
    int sv = srcArr[eidx];
    float g0[4], bh[4], pe[4], ev[4];
    up4(*(const uint2*)(G0Bh + (size_t)sv * 512 + f), g0);
    up4(*(const uint2*)(G0Bh + (size_t)sv * 512 + 256 + f), bh);
    up4(*(const uint2*)(Pe + (size_t)li * 256 + f), pe);
    up4(*(const uint2*)(e + (size_t)eidx * 256 + f), ev);
    float t[4];
#pragma unroll
    for (int k = 0; k < 4; ++k) {
      float sg = sigm(g0[k] + g1v[k] + pe[k]);
      t[k] = sg * ev[k];
      ssh[k] = fmaf(bh[k], sg, ssh[k]);
      ssm[k] += sg;
    }
    float s1 = wsum64(t[0] + t[1] + t[2] + t[3]);
    float s2 = wsum64(t[0] * t[0] + t[1] * t[1] + t[2] * t[2] + t[3] * t[3]);
    float mn = s1 * (1.f / 256.f);
    float rs = rsqrtf(s2 * (1.f / 256.f) - mn * mn + 1e-5f);
    float o[4];
#pragma unroll
    for (int k = 0; k < 4; ++k) o[k] = (t[k] - mn) * rs * lwe[k] + lbe[k];
    *(uint2*)(e + (size_t)eidx * 256 + f) = pk4(o);
  }
  float tt[4];
#pragma unroll
  for (int k = 0; k < 4; ++k) tt[k] = ah[k] + ssh[k] / (ssm[k] + 1e-8f);
  float s1 = wsum64(tt[0] + tt[1] + tt[2] + tt[3]);
  float s2 = wsum64(tt[0] * tt[0] + tt[1] * tt[1] + tt[2] * tt[2] + tt[3] * tt[3]);
  float mn = s1 * (1.f / 256.f);
  float rs = rsqrtf(s2 * (1.f / 256.f) - mn * mn + 1e-5f);
  float o[4];
#pragma unroll
  for (int k = 0; k < 4; ++k) o[k] = (tt[k] - mn) * rs * lwn[k] + lbn[k];
  *(uint2*)(h + (size_t)v * 256 + f) = pk4(o);
}

// ---------------- readout ----------------
__global__ __launch_bounds__(256) void pool_acc(
    const u16* __restrict__ x, const int* __restrict__ gid,
    float* __restrict__ out, float* __restrict__ cnt, int n) {
  int v = (blockIdx.x * 256 + threadIdx.x) >> 6;
  if (v >= n) return;
  int lane = threadIdx.x & 63;
  int f = lane * 4;
  int g = gid[v];
  float xv[4];
  up4(*(const uint2*)(x + (size_t)v * 256 + f), xv);
  float* p = out + (size_t)g * 256 + f;
  unsafeAtomicAdd(p + 0, xv[0]);
  unsafeAtomicAdd(p + 1, xv[1]);
  unsafeAtomicAdd(p + 2, xv[2]);
  unsafeAtomicAdd(p + 3, xv[3]);
  if (lane == 0) unsafeAtomicAdd(cnt + g, 1.0f);
}
__global__ __launch_bounds__(256) void pool_div(float* __restrict__ out,
                                                const float* __restrict__ cnt, int n) {
  int i = blockIdx.x * blockDim.x + threadIdx.x;
  if (i < n) out[i] /= fmaxf(cnt[i >> 8], 1.0f);
}

// ---------------- host ----------------
extern "C" void kernel_launch(void* const* d_in, const int* in_sizes, int n_in,
                              void* d_out, int out_size, void* d_ws, size_t ws_size,
                              hipStream_t stream) {
  const float* atom_features = (const float*)d_in[0];
  const float* bondlength    = (const float*)d_in[1];
  const float* angle_h       = (const float*)d_in[2];
  const int*   src           = (const int*)d_in[3];
  const int*   dst           = (const int*)d_in[4];
  const int*   lg_src        = (const int*)d_in[5];
  const int*   lg_dst        = (const int*)d_in[6];
  const int*   gid           = (const int*)d_in[7];
  const float* atom_W  = (const float*)d_in[8];
  const float* atom_b  = (const float*)d_in[9];
  const float* atom_ln = (const float*)d_in[10];
  const float* edge_W1 = (const float*)d_in[11];
  const float* edge_b1 = (const float*)d_in[12];
  const float* edge_ln1= (const float*)d_in[13];
  const float* edge_W2 = (const float*)d_in[14];
  const float* edge_b2 = (const float*)d_in[15];
  const float* edge_ln2= (const float*)d_in[16];
  const float* ang_W1  = (const float*)d_in[17];
  const float* ang_b1  = (const float*)d_in[18];
  const float* ang_ln1 = (const float*)d_in[19];
  const float* ang_W2  = (const float*)d_in[20];
  const float* ang_b2  = (const float*)d_in[21];
  const float* ang_ln2 = (const float*)d_in[22];
  const float* conv_W  = (const float*)d_in[23];
  const float* conv_b  = (const float*)d_in[24];
  const float* conv_lns= (const float*)d_in[25];
  const float* conv_lnb= (const float*)d_in[26];

  int N = in_sizes[0] / 92;
  int E = in_sizes[1];
  int T = in_sizes[2];

  // ---- workspace layout (bytes) ----
  char* ws = (char*)d_ws;
  size_t o = 0;
  auto alloc = [&](size_t bytes) { size_t r = o; o = (o + bytes + 255) & ~(size_t)255; return r; };
  u16* z     = (u16*)(ws + alloc((size_t)T * 512));
  u16* y     = (u16*)(ws + alloc((size_t)E * 512));
  u16* x     = (u16*)(ws + alloc((size_t)N * 512));
  int* eidL  = (int*)(ws + alloc((size_t)T * 4));
  int* offsL = (int*)(ws + alloc((size_t)(E + 1) * 4));
  int* eidA  = (int*)(ws + alloc((size_t)E * 4));
  int* offsA = (int*)(ws + alloc((size_t)(N + 1) * 4));
  int* tmp   = (int*)(ws + alloc((size_t)(E > N ? E : N) * 4));
  int* bsum  = (int*)(ws + alloc(1024));
  float* cnt = (float*)(ws + alloc(1024));
  u16* WtAll = (u16*)(ws + alloc((size_t)12 * 5 * 65536 * 2));  // 7.86 MB
  u16* WtAng = (u16*)(ws + alloc((size_t)16384 * 2));
  u16* WtEdg = (u16*)(ws + alloc((size_t)16384 * 2));
  size_t layer_base = o;

  if (ws_size < layer_base + (size_t)2 * 1024 * 1024) {
    fill_kernel<<<(out_size + 255) / 256, 256, 0, stream>>>(
        (float*)d_out, out_size, (float)(ws_size >> 20));
    return;
  }
  size_t avail = ws_size - layer_base;

  // chunk picker: maximize VC s.t. G0Bh + G1Ah(VC) + Pe(cap) fits
  auto pick = [&](long long nn_, long long ne_, int& VC, int& EC) -> bool {
    long long sub = (long long)avail - nn_ * 1024;
    if (sub < (1 << 20)) return false;
    for (long long vc = (nn_ + 255) & ~255LL; vc >= 256; vc -= 256) {
      long long mean = ne_ * vc / nn_;
      long long cap = mean + mean / 8 + 1024;
      if (cap > ne_) cap = ne_;
      if (vc * 1024 + cap * 512 <= sub) {
        long long ec = (sub - vc * 1024) / 512;
        if (ec > ne_) ec = ne_;
        VC = (int)vc; EC = (int)ec;
        return true;
      }
    }
    return false;
  };
  int VCL = 0, ECL = 0, VCA = 0, ECA = 0;
  if (!pick(E, T, VCL, ECL) || !pick(N, E, VCA, ECA)) {
    fill_kernel<<<(out_size + 255) / 256, 256, 0, stream>>>(
        (float*)d_out, out_size, 1000000.0f + (float)(ws_size >> 20));
    return;
  }

  // ---- weight transposes (bf16, n-major) ----
  wtrans<<<dim3(4, 4, 60), 256, 0, stream>>>(conv_W, WtAll, 256, 256);
  wtrans<<<dim3(1, 4, 1), 256, 0, stream>>>(ang_W2, WtAng, 64, 256);
  wtrans<<<dim3(1, 4, 1), 256, 0, stream>>>(edge_W2, WtEdg, 64, 256);

  // ---- CSR build ----
  auto build_csr = [&](const int* dvec, int ne_, int nn_, int* offs_, int* eid_) {
    hipMemsetAsync(tmp, 0, (size_t)nn_ * 4, stream);
    csr_hist<<<(ne_ + 255) / 256, 256, 0, stream>>>(dvec, tmp, ne_);
    int nb = (nn_ + 1023) / 1024;
    scan1<<<nb, 1024, 0, stream>>>(tmp, offs_ + 1, bsum, nn_);
    scan2<<<1, 128, 0, stream>>>(bsum, nb);
    scan3<<<(nn_ + 255) / 256, 256, 0, stream>>>(offs_, bsum, nn_);
    hipMemsetAsync(tmp, 0, (size_t)nn_ * 4, stream);
    csr_scatter<<<(ne_ + 255) / 256, 256, 0, stream>>>(dvec, tmp, offs_, eid_, ne_);
  };
  build_csr(lg_dst, T, E, offsL, eidL);
  build_csr(dst, E, N, offsA, eidA);

  // ---- embeddings: stage1 -> MFMA GEMM (K=64) -> LN+SiLU epilogue ----
  u16* t1T = (u16*)(ws + layer_base);
  u16* t1E = t1T + (size_t)T * 64;
  embed_s1<<<(T + 3) / 4, 256, 0, stream>>>(angle_h, ang_W1, ang_b1, ang_ln1,
                                            t1T, T, 40, -1.f, 1.f);
  embed_s1<<<(E + 3) / 4, 256, 0, stream>>>(bondlength, edge_W1, edge_b1, edge_ln1,
                                            t1E, E, 80, 0.f, 8.f);
  mfma_gemm<<<dim3((T + 127) / 128, 2), 256, 0, stream>>>(
      t1T, WtAng, ang_b2, z, T, 64, 256, 1, nullptr, nullptr, 0, 0);
  mfma_gemm<<<dim3((E + 127) / 128, 2), 256, 0, stream>>>(
      t1E, WtEdg, edge_b2, y, E, 64, 256, 1, nullptr, nullptr, 0, 0);
  ln_silu<<<(T + 3) / 4, 256, 0, stream>>>(z, ang_ln2, T);
  ln_silu<<<(E + 3) / 4, 256, 0, stream>>>(y, edge_ln2, E);
  atom_embed_kernel<<<N, 256, 0, stream>>>(atom_features, atom_W, atom_b, atom_ln, x, N);

  // ---- 12 EGGC layers ----
  for (int l = 0; l < 12; ++l) {
    const u16* WtL  = WtAll + (size_t)l * 5 * 65536;
    const float* bl = conv_b + (size_t)l * 5 * 256;
    const float* lnS = conv_lns + (size_t)l * 512;
    const float* lnB = conv_lnb + (size_t)l * 512;
    bool line = (l < 8) && ((l & 1) == 0);
    u16* h = line ? y : x;
    u16* e = line ? z : y;
    const int* sp   = line ? lg_src : src;
    const int* eidG = line ? eidL : eidA;
    const int* offs = line ? offsL : offsA;
    int nn = line ? E : N;
    int ne = line ? T : E;
    int VC = line ? VCL : VCA;
    int EC = line ? ECL : ECA;

    u16* G0Bh = (u16*)(ws + layer_base);
    u16* G1Ah = G0Bh + (size_t)nn * 512;
    u16* Pe   = G1Ah + (size_t)VC * 512;

    // G0Bh = h @ [W0|W4] + [b0|b4]   (slab_step=4)
    mfma_gemm<<<dim3((nn + 127) / 128, 4), 256, 0, stream>>>(
        h, WtL, bl, G0Bh, nn, 256, 512, 4, nullptr, nullptr, 0, 0);
    for (int v0 = 0; v0 < nn; v0 += VC) {
      int v1 = min(v0 + VC, nn);
      int cn = v1 - v0;
      // G1Ah = h[v0:v1] @ [W1|W3] + [b1|b3]  (slab_step=2)
      mfma_gemm<<<dim3((cn + 127) / 128, 4), 256, 0, stream>>>(
          h + (size_t)v0 * 256, WtL + 65536, bl + 256, G1Ah, cn, 256, 512, 2,
          nullptr, nullptr, 0, 0);
      // Pe = e[eid[offs[v0]:offs[v1]]] @ W2 + b2 (row gather, chunk-local)
      mfma_gemm<<<dim3((EC + 127) / 128, 2), 256, 0, stream>>>(
          e, WtL + 2 * 65536, bl + 2 * 256, Pe, EC, 256, 256, 1,
          eidG, offs, v0, v1);
      eggc_fused<<<(cn + 3) / 4, 256, 0, stream>>>(sp, eidG, offs, v0, v1,
                                                   G0Bh, G1Ah, Pe, EC, e, h, lnS, lnB);
    }
  }

  // ---- readout ----
  hipMemsetAsync(d_out, 0, (size_t)out_size * sizeof(float), stream);
  hipMemsetAsync(cnt, 0, 256 * sizeof(float), stream);
  pool_acc<<<(N + 3) / 4, 256, 0, stream>>>(x, gid, (float*)d_out, cnt, N);
  pool_div<<<(out_size + 255) / 256, 256, 0, stream>>>((float*)d_out, cnt, out_size);
}

// Round 7
// 5468.967 us; speedup vs baseline: 2.4963x; 1.3953x over previous
//
#include <hip/hip_runtime.h>
#include <hip/hip_bf16.h>

typedef unsigned short u16;
typedef unsigned int u32;
typedef __attribute__((ext_vector_type(8))) short short8;
typedef __attribute__((ext_vector_type(4))) float f32x4;

// ---------------- helpers ----------------
__device__ __forceinline__ float bf2f(u16 u) { return __uint_as_float(((u32)u) << 16); }
__device__ __forceinline__ u16 f2bf(float f) {
  u32 x = __float_as_uint(f);
  return (u16)((x + 0x7FFFu + ((x >> 16) & 1u)) >> 16);
}
__device__ __forceinline__ void up4(uint2 r, float* o) {
  o[0] = bf2f((u16)(r.x & 0xFFFF)); o[1] = bf2f((u16)(r.x >> 16));
  o[2] = bf2f((u16)(r.y & 0xFFFF)); o[3] = bf2f((u16)(r.y >> 16));
}
__device__ __forceinline__ uint2 pk4(const float* o) {
  uint2 r;
  r.x = (u32)f2bf(o[0]) | ((u32)f2bf(o[1]) << 16);
  r.y = (u32)f2bf(o[2]) | ((u32)f2bf(o[3]) << 16);
  return r;
}
__device__ __forceinline__ float wsum64(float v) {
#pragma unroll
  for (int o = 32; o > 0; o >>= 1) v += __shfl_xor(v, o, 64);
  return v;
}
__device__ __forceinline__ float sigm(float x) { return 1.0f / (1.0f + __expf(-x)); }

__global__ __launch_bounds__(256) void fill_kernel(float* __restrict__ out, int n, float v) {
  int i = blockIdx.x * 256 + threadIdx.x;
  if (i < n) out[i] = v;
}

// ---------------- weight transpose: in[k][n] f32 -> out[n][k] bf16 ----------------
__global__ __launch_bounds__(256) void wtrans(const float* __restrict__ in,
                                              u16* __restrict__ out, int R, int Ccols) {
  __shared__ float t[64][65];
  const float* ip = in + (size_t)blockIdx.z * R * Ccols;
  u16* op = out + (size_t)blockIdx.z * R * Ccols;
  int kb = blockIdx.x * 64, nb = blockIdx.y * 64;
  int lr = threadIdx.x >> 4, lc = (threadIdx.x & 15) * 4;
#pragma unroll
  for (int p = 0; p < 4; ++p) {
    int k = lr + p * 16;
    float4 v = *(const float4*)(ip + (size_t)(kb + k) * Ccols + nb + lc);
    t[k][lc + 0] = v.x; t[k][lc + 1] = v.y; t[k][lc + 2] = v.z; t[k][lc + 3] = v.w;
  }
  __syncthreads();
#pragma unroll
  for (int p = 0; p < 4; ++p) {
    int n = lr + p * 16;
    uint2 pk;
    pk.x = (u32)f2bf(t[lc + 0][n]) | ((u32)f2bf(t[lc + 1][n]) << 16);
    pk.y = (u32)f2bf(t[lc + 2][n]) | ((u32)f2bf(t[lc + 3][n]) << 16);
    *(uint2*)(op + (size_t)(nb + n) * R + kb + lc) = pk;
  }
}

// ---------------- CSR build ----------------
__global__ __launch_bounds__(256) void csr_hist(const int* __restrict__ dst,
                                                int* __restrict__ hist, int ne) {
  int e = blockIdx.x * 256 + threadIdx.x;
  if (e < ne) atomicAdd(&hist[dst[e]], 1);
}
__global__ __launch_bounds__(1024) void scan1(const int* __restrict__ in,
                                              int* __restrict__ out1, int* __restrict__ bsum, int n) {
  __shared__ int s[1024];
  int i = blockIdx.x * 1024 + threadIdx.x;
  int v = (i < n) ? in[i] : 0;
  s[threadIdx.x] = v; __syncthreads();
  for (int off = 1; off < 1024; off <<= 1) {
    int t = (threadIdx.x >= (u32)off) ? s[threadIdx.x - off] : 0;
    __syncthreads();
    s[threadIdx.x] += t;
    __syncthreads();
  }
  if (i < n) out1[i] = s[threadIdx.x];
  if (threadIdx.x == 1023) bsum[blockIdx.x] = s[1023];
}
__global__ __launch_bounds__(128) void scan2(int* __restrict__ bsum, int nb) {
  __shared__ int s[128];
  int v = (threadIdx.x < (u32)nb) ? bsum[threadIdx.x] : 0;
  s[threadIdx.x] = v; __syncthreads();
  for (int off = 1; off < 128; off <<= 1) {
    int t = (threadIdx.x >= (u32)off) ? s[threadIdx.x - off] : 0;
    __syncthreads();
    s[threadIdx.x] += t;
    __syncthreads();
  }
  if (threadIdx.x < (u32)nb) bsum[threadIdx.x] = threadIdx.x ? s[threadIdx.x - 1] : 0;
}
__global__ __launch_bounds__(256) void scan3(int* __restrict__ offs,
                                             const int* __restrict__ bsum, int n) {
  int i = blockIdx.x * 256 + threadIdx.x;
  if (i == 0) offs[0] = 0;
  if (i < n) offs[1 + i] += bsum[i >> 10];
}
__global__ __launch_bounds__(256) void csr_scatter(const int* __restrict__ dst,
                                                   int* __restrict__ cursor,
                                                   const int* __restrict__ offs,
                                                   int* __restrict__ eid, int ne) {
  int e = blockIdx.x * 256 + threadIdx.x;
  if (e < ne) {
    int d = dst[e];
    int p = offs[d] + atomicAdd(&cursor[d], 1);
    eid[p] = e;
  }
}
__global__ __launch_bounds__(256) void inv_perm(const int* __restrict__ eid,
                                                int* __restrict__ pos, int n) {
  int i = blockIdx.x * 256 + threadIdx.x;
  if (i < n) pos[eid[i]] = i;
}
__global__ __launch_bounds__(256) void remap_k(const int* __restrict__ idx,
                                               const int* __restrict__ map,
                                               int* __restrict__ out, int n) {
  int i = blockIdx.x * 256 + threadIdx.x;
  if (i < n) out[i] = map[idx[i]];
}
__global__ __launch_bounds__(256) void compose_src(const int* __restrict__ eid,
                                                   const int* __restrict__ srcv,
                                                   const int* __restrict__ map,
                                                   int* __restrict__ out, int n) {
  int i = blockIdx.x * 256 + threadIdx.x;
  if (i < n) {
    int s = srcv[eid[i]];
    out[i] = map ? map[s] : s;
  }
}

// ---------------- embeddings ----------------
// stage1: wave per row: rbf(bins) -> W1[bins,64]+b1 -> LN64 -> SiLU -> t1 bf16[perm[row],64]
__global__ __launch_bounds__(256) void embed_s1(
    const float* __restrict__ xin, const float* __restrict__ W1,
    const float* __restrict__ b1, const float* __restrict__ ln1,
    u16* __restrict__ t1, int rows, int bins, float vmin, float vmax,
    const int* __restrict__ perm) {
  int row = (blockIdx.x * 256 + threadIdx.x) >> 6;
  if (row >= rows) return;
  int lane = threadIdx.x & 63;
  float xv = xin[row];
  float rng = vmax - vmin;
  float step = rng / (float)(bins - 1);
  float gamma = 0.5f * ((float)bins / rng) * ((float)bins / rng);
  float rb = 0.f, rb2 = 0.f;
  if (lane < bins) {
    float d = xv - (vmin + lane * step);
    rb = __expf(-gamma * d * d);
  }
  if (bins > 64 && lane < bins - 64) {
    float d = xv - (vmin + (lane + 64) * step);
    rb2 = __expf(-gamma * d * d);
  }
  float u = b1[lane];
  int k1 = bins < 64 ? bins : 64;
  for (int k = 0; k < k1; ++k) {
    float rv = __shfl(rb, k, 64);
    u = fmaf(rv, W1[k * 64 + lane], u);
  }
  for (int k = 64; k < bins; ++k) {
    float rv = __shfl(rb2, k - 64, 64);
    u = fmaf(rv, W1[k * 64 + lane], u);
  }
  float s = wsum64(u), s2 = wsum64(u * u);
  float m = s * (1.f / 64.f), var = s2 * (1.f / 64.f) - m * m;
  float t = (u - m) * rsqrtf(var + 1e-5f) * ln1[lane] + ln1[64 + lane];
  int orow = perm ? perm[row] : row;
  t1[(size_t)orow * 64 + lane] = f2bf(t * sigm(t));
}

// in-place LN(256) + SiLU on bf16 [rows,256]
__global__ __launch_bounds__(256) void ln_silu(u16* __restrict__ buf,
                                               const float* __restrict__ ln, int rows) {
  int row = (blockIdx.x * 256 + threadIdx.x) >> 6;
  if (row >= rows) return;
  int lane = threadIdx.x & 63;
  int f = lane * 4;
  float v[4];
  up4(*(const uint2*)(buf + (size_t)row * 256 + f), v);
  float s = wsum64(v[0] + v[1] + v[2] + v[3]);
  float s2 = wsum64(v[0] * v[0] + v[1] * v[1] + v[2] * v[2] + v[3] * v[3]);
  float m = s * (1.f / 256.f);
  float rs = rsqrtf(s2 * (1.f / 256.f) - m * m + 1e-5f);
  float o[4];
#pragma unroll
  for (int k = 0; k < 4; ++k) {
    float t = (v[k] - m) * rs * ln[f + k] + ln[256 + f + k];
    o[k] = t * sigm(t);
  }
  *(uint2*)(buf + (size_t)row * 256 + f) = pk4(o);
}

// atom_features[N,92] @ W[92,256] + b -> LN -> SiLU
__global__ __launch_bounds__(256) void atom_embed_kernel(
    const float* __restrict__ af, const float* __restrict__ W,
    const float* __restrict__ b, const float* __restrict__ ln,
    u16* __restrict__ out, int rows) {
  int row = blockIdx.x;
  if (row >= rows) return;
  __shared__ float a_s[92];
  __shared__ float red[8];
  int tid = threadIdx.x;
  if (tid < 92) a_s[tid] = af[(size_t)row * 92 + tid];
  __syncthreads();
  float v = b[tid];
#pragma unroll 4
  for (int k = 0; k < 92; ++k) v = fmaf(a_s[k], W[k * 256 + tid], v);
  float s = wsum64(v), s2 = wsum64(v * v);
  int lane = tid & 63, wid = tid >> 6;
  if (lane == 0) { red[wid] = s; red[4 + wid] = s2; }
  __syncthreads();
  s = red[0] + red[1] + red[2] + red[3];
  s2 = red[4] + red[5] + red[6] + red[7];
  float m = s * (1.f / 256.f), var = s2 * (1.f / 256.f) - m * m;
  float t = (v - m) * rsqrtf(var + 1e-5f) * ln[tid] + ln[256 + tid];
  out[(size_t)row * 256 + tid] = f2bf(t * sigm(t));
}

// ---------------- MFMA GEMM: C[M,ldc](bf16) = A[M,K](bf16) @ W + bias ----------------
// Wt: bf16 transposed slabs [256 n][K k]; col block bn -> slab (bn>>8)*slab_step.
__global__ __launch_bounds__(256) void mfma_gemm(
    const u16* __restrict__ A, const u16* __restrict__ Wt,
    const float* __restrict__ bias, u16* __restrict__ C,
    int M, int K, int ldc, int slab_step) {
  int bm = blockIdx.x * 128;
  if (bm >= M) return;
  int bn = blockIdx.y * 128;
  int slab = (bn >> 8) * slab_step;
  const u16* Wp = Wt + (size_t)slab * 256 * K + (size_t)(bn & 255) * K;
  const float* bp = bias + slab * 256 + (bn & 255);
  int tid = threadIdx.x;
  int w = tid >> 6, lane = tid & 63;
  int q = lane >> 4, r = lane & 15;
  int m0 = (w & 1) * 64;
  int n0 = (w >> 1) * 64;
  const u16* aptr[4];
#pragma unroll
  for (int mi = 0; mi < 4; ++mi) {
    int m = bm + m0 + mi * 16 + r;
    m = m < M - 1 ? m : M - 1;
    aptr[mi] = A + (size_t)m * K + q * 8;
  }
  const u16* wptr[4];
#pragma unroll
  for (int ni = 0; ni < 4; ++ni)
    wptr[ni] = Wp + (size_t)(n0 + ni * 16 + r) * K + q * 8;
  f32x4 acc[4][4] = {};
  for (int kb = 0; kb < K; kb += 32) {
    short8 bfr[4], afr[4];
#pragma unroll
    for (int mi = 0; mi < 4; ++mi) bfr[mi] = *(const short8*)(aptr[mi] + kb);
#pragma unroll
    for (int ni = 0; ni < 4; ++ni) afr[ni] = *(const short8*)(wptr[ni] + kb);
#pragma unroll
    for (int mi = 0; mi < 4; ++mi)
#pragma unroll
      for (int ni = 0; ni < 4; ++ni)
        acc[mi][ni] = __builtin_amdgcn_mfma_f32_16x16x32_bf16(afr[ni], bfr[mi],
                                                              acc[mi][ni], 0, 0, 0);
  }
#pragma unroll
  for (int mi = 0; mi < 4; ++mi) {
    int m = bm + m0 + mi * 16 + r;
    if (m < M) {
#pragma unroll
      for (int ni = 0; ni < 4; ++ni) {
        int n = n0 + ni * 16 + q * 4;
        float4 bv = *(const float4*)(bp + n);
        uint2 o;
        o.x = (u32)f2bf(acc[mi][ni].x + bv.x) | ((u32)f2bf(acc[mi][ni].y + bv.y) << 16);
        o.y = (u32)f2bf(acc[mi][ni].z + bv.z) | ((u32)f2bf(acc[mi][ni].w + bv.w) << 16);
        *(uint2*)(C + (size_t)m * ldc + bn + n) = o;
      }
    }
  }
}

// ---------------- mega-fused EGGC ----------------
// Block = 16 dst nodes (8 waves, 512 thr). Edge rows of e are CSR-contiguous per dst range.
// Phase A: g1ah[16][512] = h[v0..v0+16) @ [W1|W3] + [b1|b3]  (LDS)
// Loop: Phase B: pe[64][256] = e[ec..ec+64) @ W2 + b2 (LDS); Phase C: wave-per-dst (2 each)
//   walks its CSR edges in chunk: sigma, edge-LN in-place on e, accumulate ssh/ssm in regs.
// Phase D: node update + LN in-place on h rows [v0..v0+16).
__global__ __launch_bounds__(512) void mega_eggc(
    u16* __restrict__ h, u16* __restrict__ e,
    const u16* __restrict__ G0Bh,
    const u16* __restrict__ Wt13, const float* __restrict__ b13,
    const u16* __restrict__ Wt2, const float* __restrict__ b2v,
    const int* __restrict__ src_perm, const int* __restrict__ offs,
    const float* __restrict__ lnS, const float* __restrict__ lnB, int nn) {
  __shared__ u16 g1ah[16][520];
  __shared__ u16 pe[64][264];
  int tid = threadIdx.x;
  int w = tid >> 6, lane = tid & 63;
  int q = lane >> 4, r = lane & 15;
  int v0 = blockIdx.x * 16;

  // ---- Phase A ----
  {
    int mrow = v0 + r; if (mrow > nn - 1) mrow = nn - 1;
    const u16* arow = h + (size_t)mrow * 256 + q * 8;
    f32x4 acc[4] = {};
    for (int kb = 0; kb < 256; kb += 32) {
      short8 af = *(const short8*)(arow + kb);
#pragma unroll
      for (int t = 0; t < 4; ++t) {
        int ng = (4 * w + t) * 16 + r;
        const u16* wrow = Wt13 + (size_t)(ng >> 8) * 2 * 65536 +
                          (size_t)(ng & 255) * 256 + q * 8;
        short8 wf = *(const short8*)(wrow + kb);
        acc[t] = __builtin_amdgcn_mfma_f32_16x16x32_bf16(wf, af, acc[t], 0, 0, 0);
      }
    }
#pragma unroll
    for (int t = 0; t < 4; ++t) {
      int nb = (4 * w + t) * 16 + q * 4;
      const float* bp = b13 + (nb >> 8) * 2 * 256 + (nb & 255);
      float o[4] = {acc[t].x + bp[0], acc[t].y + bp[1], acc[t].z + bp[2], acc[t].w + bp[3]};
      *(uint2*)&g1ah[r][nb] = pk4(o);
    }
  }
  __syncthreads();

  int f = lane * 4;
  int r0 = offs[v0];
  int vend = v0 + 16 < nn ? v0 + 16 : nn;
  int r1 = offs[vend];
  int vA = v0 + w * 2, vB = vA + 1;
  int eA0 = vA < nn ? offs[vA] : 0, eA1 = vA < nn ? offs[vA + 1] : 0;
  int eB0 = vB < nn ? offs[vB] : 0, eB1 = vB < nn ? offs[vB + 1] : 0;
  float sshA[4] = {0, 0, 0, 0}, ssmA[4] = {0, 0, 0, 0};
  float sshB[4] = {0, 0, 0, 0}, ssmB[4] = {0, 0, 0, 0};
  float lwe[4], lbe[4];
#pragma unroll
  for (int k = 0; k < 4; ++k) { lwe[k] = lnS[f + k]; lbe[k] = lnB[f + k]; }

  for (int ec = r0; ec < r1; ec += 64) {
    // ---- Phase B ----
    {
      const u16* w0p = Wt2 + (size_t)((2 * w) * 16 + r) * 256 + q * 8;
      const u16* w1p = Wt2 + (size_t)((2 * w + 1) * 16 + r) * 256 + q * 8;
      f32x4 acc[4][2] = {};
      for (int kb = 0; kb < 256; kb += 32) {
        short8 wf0 = *(const short8*)(w0p + kb);
        short8 wf1 = *(const short8*)(w1p + kb);
#pragma unroll
        for (int mt = 0; mt < 4; ++mt) {
          int erow = ec + mt * 16 + r;
          if (erow > r1 - 1) erow = r1 - 1;
          short8 af = *(const short8*)(e + (size_t)erow * 256 + kb + q * 8);
          acc[mt][0] = __builtin_amdgcn_mfma_f32_16x16x32_bf16(wf0, af, acc[mt][0], 0, 0, 0);
          acc[mt][1] = __builtin_amdgcn_mfma_f32_16x16x32_bf16(wf1, af, acc[mt][1], 0, 0, 0);
        }
      }
#pragma unroll
      for (int mt = 0; mt < 4; ++mt)
#pragma unroll
        for (int nt = 0; nt < 2; ++nt) {
          int nb = (2 * w + nt) * 16 + q * 4;
          float o[4] = {acc[mt][nt].x + b2v[nb], acc[mt][nt].y + b2v[nb + 1],
                        acc[mt][nt].z + b2v[nb + 2], acc[mt][nt].w + b2v[nb + 3]};
          *(uint2*)&pe[mt * 16 + r][nb] = pk4(o);
        }
    }
    __syncthreads();
    // ---- Phase C ----
    int ce = ec + 64 < r1 ? ec + 64 : r1;
#pragma unroll
    for (int jj = 0; jj < 2; ++jj) {
      int vv = jj ? vB : vA;
      int i0 = jj ? eB0 : eA0, i1 = jj ? eB1 : eA1;
      int lo = i0 > ec ? i0 : ec, hi = i1 < ce ? i1 : ce;
      for (int i = lo; i < hi; ++i) {
        int sv = src_perm[i];
        float g0[4], bh[4], pv[4], ev[4], g1v[4];
        up4(*(const uint2*)(G0Bh + (size_t)sv * 512 + f), g0);
        up4(*(const uint2*)(G0Bh + (size_t)sv * 512 + 256 + f), bh);
        up4(*(const uint2*)&pe[i - ec][f], pv);
        up4(*(const uint2*)(e + (size_t)i * 256 + f), ev);
        up4(*(const uint2*)&g1ah[vv - v0][f], g1v);
        float t[4];
        float ssum = 0.f, s2sum = 0.f;
#pragma unroll
        for (int k = 0; k < 4; ++k) {
          float sg = sigm(g0[k] + g1v[k] + pv[k]);
          t[k] = sg * ev[k];
          if (jj) { sshB[k] = fmaf(bh[k], sg, sshB[k]); ssmB[k] += sg; }
          else    { sshA[k] = fmaf(bh[k], sg, sshA[k]); ssmA[k] += sg; }
          ssum += t[k]; s2sum += t[k] * t[k];
        }
        float s1 = wsum64(ssum), s2 = wsum64(s2sum);
        float mn = s1 * (1.f / 256.f);
        float rs = rsqrtf(s2 * (1.f / 256.f) - mn * mn + 1e-5f);
        float o[4];
#pragma unroll
        for (int k = 0; k < 4; ++k) o[k] = (t[k] - mn) * rs * lwe[k] + lbe[k];
        *(uint2*)(e + (size_t)i * 256 + f) = pk4(o);
      }
    }
    __syncthreads();
  }
  // ---- Phase D ----
#pragma unroll
  for (int jj = 0; jj < 2; ++jj) {
    int vv = jj ? vB : vA;
    if (vv < nn) {
      float ah[4], tt[4];
      up4(*(const uint2*)&g1ah[vv - v0][256 + f], ah);
      float ssum = 0.f, s2sum = 0.f;
#pragma unroll
      for (int k = 0; k < 4; ++k) {
        float sh = jj ? sshB[k] : sshA[k];
        float sm = jj ? ssmB[k] : ssmA[k];
        tt[k] = ah[k] + sh / (sm + 1e-8f);
        ssum += tt[k]; s2sum += tt[k] * tt[k];
      }
      float s1 = wsum64(ssum), s2 = wsum64(s2sum);
      float mn = s1 * (1.f / 256.f);
      float rs = rsqrtf(s2 * (1.f / 256.f) - mn * mn + 1e-5f);
      float o[4];
#pragma unroll
      for (int k = 0; k < 4; ++k)
        o[k] = (tt[k] - mn) * rs * lnS[256 + f + k] + lnB[256 + f + k];
      *(uint2*)(h + (size_t)vv * 256 + f) = pk4(o);
    }
  }
}

// ---------------- readout ----------------
__global__ __launch_bounds__(256) void pool_acc(
    const u16* __restrict__ x, const int* __restrict__ gid,
    float* __restrict__ out, float* __restrict__ cnt, int n) {
  int v = (blockIdx.x * 256 + threadIdx.x) >> 6;
  if (v >= n) return;
  int lane = threadIdx.x & 63;
  int f = lane * 4;
  int g = gid[v];
  float xv[4];
  up4(*(const uint2*)(x + (size_t)v * 256 + f), xv);
  float* p = out + (size_t)g * 256 + f;
  unsafeAtomicAdd(p + 0, xv[0]);
  unsafeAtomicAdd(p + 1, xv[1]);
  unsafeAtomicAdd(p + 2, xv[2]);
  unsafeAtomicAdd(p + 3, xv[3]);
  if (lane == 0) unsafeAtomicAdd(cnt + g, 1.0f);
}
__global__ __launch_bounds__(256) void pool_div(float* __restrict__ out,
                                                const float* __restrict__ cnt, int n) {
  int i = blockIdx.x * blockDim.x + threadIdx.x;
  if (i < n) out[i] /= fmaxf(cnt[i >> 8], 1.0f);
}

// ---------------- host ----------------
extern "C" void kernel_launch(void* const* d_in, const int* in_sizes, int n_in,
                              void* d_out, int out_size, void* d_ws, size_t ws_size,
                              hipStream_t stream) {
  const float* atom_features = (const float*)d_in[0];
  const float* bondlength    = (const float*)d_in[1];
  const float* angle_h       = (const float*)d_in[2];
  const int*   src           = (const int*)d_in[3];
  const int*   dst           = (const int*)d_in[4];
  const int*   lg_src        = (const int*)d_in[5];
  const int*   lg_dst        = (const int*)d_in[6];
  const int*   gid           = (const int*)d_in[7];
  const float* atom_W  = (const float*)d_in[8];
  const float* atom_b  = (const float*)d_in[9];
  const float* atom_ln = (const float*)d_in[10];
  const float* edge_W1 = (const float*)d_in[11];
  const float* edge_b1 = (const float*)d_in[12];
  const float* edge_ln1= (const float*)d_in[13];
  const float* edge_W2 = (const float*)d_in[14];
  const float* edge_b2 = (const float*)d_in[15];
  const float* edge_ln2= (const float*)d_in[16];
  const float* ang_W1  = (const float*)d_in[17];
  const float* ang_b1  = (const float*)d_in[18];
  const float* ang_ln1 = (const float*)d_in[19];
  const float* ang_W2  = (const float*)d_in[20];
  const float* ang_b2  = (const float*)d_in[21];
  const float* ang_ln2 = (const float*)d_in[22];
  const float* conv_W  = (const float*)d_in[23];
  const float* conv_b  = (const float*)d_in[24];
  const float* conv_lns= (const float*)d_in[25];
  const float* conv_lnb= (const float*)d_in[26];

  int N = in_sizes[0] / 92;
  int E = in_sizes[1];
  int T = in_sizes[2];

  // ---- workspace layout ----
  char* ws = (char*)d_ws;
  size_t o = 0;
  auto alloc = [&](size_t bytes) { size_t r = o; o = (o + bytes + 255) & ~(size_t)255; return r; };
  u16* z     = (u16*)(ws + alloc((size_t)T * 512));   // line-edge feats, pL-permuted
  u16* y     = (u16*)(ws + alloc((size_t)E * 512));   // atom-edge feats, pA-permuted
  u16* x     = (u16*)(ws + alloc((size_t)N * 512));   // atom feats, natural
  int* offsL = (int*)(ws + alloc((size_t)(E + 1) * 4));
  int* offsA = (int*)(ws + alloc((size_t)(N + 1) * 4));
  int* spL   = (int*)(ws + alloc((size_t)T * 4));     // line src (pA-space), CSR order
  int* spA   = (int*)(ws + alloc((size_t)E * 4));     // atom src (atom ids), CSR order
  int* pA    = (int*)(ws + alloc((size_t)E * 4));
  int* pL    = (int*)(ws + alloc((size_t)T * 4));
  int* eidL  = (int*)(ws + alloc((size_t)T * 4));
  int* eidA  = (int*)(ws + alloc((size_t)E * 4));
  int* ldSt  = (int*)(ws + alloc((size_t)T * 4));
  int* tmp   = (int*)(ws + alloc((size_t)(E > N ? E : N) * 4));
  int* bsum  = (int*)(ws + alloc(1024));
  float* cnt = (float*)(ws + alloc(1024));
  u16* WtAll = (u16*)(ws + alloc((size_t)12 * 5 * 65536 * 2));
  u16* WtAng = (u16*)(ws + alloc((size_t)16384 * 2));
  u16* WtEdg = (u16*)(ws + alloc((size_t)16384 * 2));
  size_t scratch_base = o;
  size_t need = scratch_base + (size_t)E * 1024;  // G0Bh line = biggest scratch user
  {
    size_t embed_need = scratch_base + ((size_t)T + E) * 128;
    if (embed_need > need) need = embed_need;
  }
  if (ws_size < need) {
    fill_kernel<<<(out_size + 255) / 256, 256, 0, stream>>>(
        (float*)d_out, out_size, (float)(ws_size >> 20));
    return;
  }

  // ---- weight transposes ----
  wtrans<<<dim3(4, 4, 60), 256, 0, stream>>>(conv_W, WtAll, 256, 256);
  wtrans<<<dim3(1, 4, 1), 256, 0, stream>>>(ang_W2, WtAng, 64, 256);
  wtrans<<<dim3(1, 4, 1), 256, 0, stream>>>(edge_W2, WtEdg, 64, 256);

  // ---- CSR + permutations ----
  auto build_csr = [&](const int* dvec, int ne_, int nn_, int* offs_, int* eid_) {
    hipMemsetAsync(tmp, 0, (size_t)nn_ * 4, stream);
    csr_hist<<<(ne_ + 255) / 256, 256, 0, stream>>>(dvec, tmp, ne_);
    int nb = (nn_ + 1023) / 1024;
    scan1<<<nb, 1024, 0, stream>>>(tmp, offs_ + 1, bsum, nn_);
    scan2<<<1, 128, 0, stream>>>(bsum, nb);
    scan3<<<(nn_ + 255) / 256, 256, 0, stream>>>(offs_, bsum, nn_);
    hipMemsetAsync(tmp, 0, (size_t)nn_ * 4, stream);
    csr_scatter<<<(ne_ + 255) / 256, 256, 0, stream>>>(dvec, tmp, offs_, eid_, ne_);
  };
  build_csr(dst, E, N, offsA, eidA);
  inv_perm<<<(E + 255) / 256, 256, 0, stream>>>(eidA, pA, E);
  compose_src<<<(E + 255) / 256, 256, 0, stream>>>(eidA, src, nullptr, spA, E);
  remap_k<<<(T + 255) / 256, 256, 0, stream>>>(lg_dst, pA, ldSt, T);
  build_csr(ldSt, T, E, offsL, eidL);
  inv_perm<<<(T + 255) / 256, 256, 0, stream>>>(eidL, pL, T);
  compose_src<<<(T + 255) / 256, 256, 0, stream>>>(eidL, lg_src, pA, spL, T);

  // ---- embeddings ----
  u16* t1T = (u16*)(ws + scratch_base);
  u16* t1E = t1T + (size_t)T * 64;
  embed_s1<<<(T + 3) / 4, 256, 0, stream>>>(angle_h, ang_W1, ang_b1, ang_ln1,
                                            t1T, T, 40, -1.f, 1.f, pL);
  embed_s1<<<(E + 3) / 4, 256, 0, stream>>>(bondlength, edge_W1, edge_b1, edge_ln1,
                                            t1E, E, 80, 0.f, 8.f, pA);
  mfma_gemm<<<dim3((T + 127) / 128, 2), 256, 0, stream>>>(
      t1T, WtAng, ang_b2, z, T, 64, 256, 1);
  mfma_gemm<<<dim3((E + 127) / 128, 2), 256, 0, stream>>>(
      t1E, WtEdg, edge_b2, y, E, 64, 256, 1);
  ln_silu<<<(T + 3) / 4, 256, 0, stream>>>(z, ang_ln2, T);
  ln_silu<<<(E + 3) / 4, 256, 0, stream>>>(y, edge_ln2, E);
  atom_embed_kernel<<<N, 256, 0, stream>>>(atom_features, atom_W, atom_b, atom_ln, x, N);

  // ---- 12 EGGC layers ----
  u16* G0Bh = (u16*)(ws + scratch_base);
  for (int l = 0; l < 12; ++l) {
    const u16* WtL  = WtAll + (size_t)l * 5 * 65536;
    const float* bl = conv_b + (size_t)l * 5 * 256;
    const float* lnS = conv_lns + (size_t)l * 512;
    const float* lnB = conv_lnb + (size_t)l * 512;
    bool line = (l < 8) && ((l & 1) == 0);
    u16* h = line ? y : x;
    u16* e = line ? z : y;
    const int* sperm = line ? spL : spA;
    const int* offs  = line ? offsL : offsA;
    int nn = line ? E : N;

    // G0Bh = h @ [W0|W4] + [b0|b4]
    mfma_gemm<<<dim3((nn + 127) / 128, 4), 256, 0, stream>>>(
        h, WtL, bl, G0Bh, nn, 256, 512, 4);
    // fused: G1Ah + Pe (LDS) + gate/LN/aggregate/LN
    mega_eggc<<<(nn + 15) / 16, 512, 0, stream>>>(
        h, e, G0Bh, WtL + 65536, bl + 256, WtL + 2 * 65536, bl + 2 * 256,
        sperm, offs, lnS, lnB, nn);
  }

  // ---- readout ----
  hipMemsetAsync(d_out, 0, (size_t)out_size * sizeof(float), stream);
  hipMemsetAsync(cnt, 0, 256 * sizeof(float), stream);
  pool_acc<<<(N + 3) / 4, 256, 0, stream>>>(x, gid, (float*)d_out, cnt, N);
  pool_div<<<(out_size + 255) / 256, 256, 0, stream>>>((float*)d_out, cnt, out_size);
}